// Round 1
// baseline (212.246 us; speedup 1.0000x reference)
//
#include <hip/hip_runtime.h>

#define N_NODES 4096
#define KNN 9

__device__ __forceinline__ bool vi_greater(float av, int aj, float bv, int bj) {
  // order: larger value first; ties -> smaller index first (matches lax.top_k)
  return (av > bv) || (av == bv && aj < bj);
}

// One 64-lane wave per row. Per-lane top-9 (static-indexed insertion sort),
// then 9 rounds of wave argmax + pop. Writes idx[row][0..8] and counts DV.
__global__ __launch_bounds__(256) void topk_kernel(const float* __restrict__ dis,
                                                   int* __restrict__ idx,
                                                   int* __restrict__ DV) {
  int wave = threadIdx.x >> 6;
  int lane = threadIdx.x & 63;
  int row = blockIdx.x * 4 + wave;

  const float* r = dis + (size_t)row * N_NODES;

  float v[9]; int ji[9];
#pragma unroll
  for (int t = 0; t < 9; ++t) { v[t] = -3.0e38f; ji[t] = 0x7fffffff; }

  for (int t = 0; t < 16; ++t) {
    int c0 = t * 256 + lane * 4;
    float4 f4 = *reinterpret_cast<const float4*>(r + c0);
    float vals[4] = {f4.x, f4.y, f4.z, f4.w};
#pragma unroll
    for (int q = 0; q < 4; ++q) {
      int c = c0 + q;
      float val = (c == row) ? -2.0e38f : vals[q];  // exclude diagonal
      if (vi_greater(val, c, v[8], ji[8])) {
        v[8] = val; ji[8] = c;
#pragma unroll
        for (int s = 8; s > 0; --s) {
          if (vi_greater(v[s], ji[s], v[s-1], ji[s-1])) {
            float tv = v[s]; v[s] = v[s-1]; v[s-1] = tv;
            int tj = ji[s]; ji[s] = ji[s-1]; ji[s-1] = tj;
          }
        }
      }
    }
  }

  // 9 extraction rounds: wave-wide argmax of per-lane heads, winner pops.
  bool has_center = false;
  int out_j[9];
#pragma unroll
  for (int rnd = 0; rnd < 9; ++rnd) {
    float mv = v[0]; int mj = ji[0];
#pragma unroll
    for (int d = 1; d < 64; d <<= 1) {
      float ov = __shfl_xor(mv, d);
      int   oj = __shfl_xor(mj, d);
      if (vi_greater(ov, oj, mv, mj)) { mv = ov; mj = oj; }
    }
    out_j[rnd] = mj;
    has_center = has_center || (mj == row);
    if (ji[0] == mj) {   // column indices are unique across lanes
#pragma unroll
      for (int s = 0; s < 8; ++s) { v[s] = v[s+1]; ji[s] = ji[s+1]; }
      v[8] = -3.0e38f; ji[8] = 0x7fffffff;
    }
  }
  if (!has_center) out_j[8] = row;   // force center into its own hyperedge

  if (lane == 0) {
#pragma unroll
    for (int t = 0; t < 9; ++t) {
      idx[row * KNN + t] = out_j[t];
      atomicAdd(&DV[out_j[t]], 1);
    }
  }
}

__global__ void dv2_kernel(const int* __restrict__ DV, float* __restrict__ dv2) {
  int i = blockIdx.x * blockDim.x + threadIdx.x;
  if (i < N_NODES) dv2[i] = rsqrtf((float)DV[i]);
}

// Exclusive prefix sum of DV[0..4095] -> off[0..4096]. Single block.
__global__ __launch_bounds__(1024) void scan_kernel(const int* __restrict__ DV,
                                                    int* __restrict__ off) {
  __shared__ int part[1024];
  int tid = threadIdx.x;
  int vals[4]; int s = 0;
#pragma unroll
  for (int q = 0; q < 4; ++q) { vals[q] = DV[tid * 4 + q]; s += vals[q]; }
  part[tid] = s;
  __syncthreads();
  for (int d = 1; d < 1024; d <<= 1) {
    int x = (tid >= d) ? part[tid - d] : 0;
    __syncthreads();
    part[tid] += x;
    __syncthreads();
  }
  int excl = (tid == 0) ? 0 : part[tid - 1];
#pragma unroll
  for (int q = 0; q < 4; ++q) { off[tid * 4 + q] = excl; excl += vals[q]; }
  if (tid == 1023) off[N_NODES] = excl;
}

// Build inverse CSR: for each (hyperedge e, slot j), append e to node idx[e][j]'s list.
__global__ void fill_csr(const int* __restrict__ idx, const int* __restrict__ off,
                         int* __restrict__ cursor, int* __restrict__ elist) {
  int t = blockIdx.x * blockDim.x + threadIdx.x;
  if (t >= N_NODES * KNN) return;
  int e = t / KNN;
  int node = idx[t];
  int p = atomicAdd(&cursor[node], 1);
  elist[off[node] + p] = e;
}

// Stage A: Z[e,f] = (1/9) * sum_{j} dv2[idx[e][j]] * Y[idx[e][j], f]
template<int F>
__global__ __launch_bounds__(F) void edge_gather(const float* __restrict__ Y,
                                                 const int* __restrict__ idx,
                                                 const float* __restrict__ dv2,
                                                 float* __restrict__ Z) {
  __shared__ int er[KNN];
  __shared__ float ew[KNN];
  int e = blockIdx.x;
  if (threadIdx.x < KNN) {
    int r = idx[e * KNN + threadIdx.x];
    er[threadIdx.x] = r;
    ew[threadIdx.x] = dv2[r];
  }
  __syncthreads();
  int f = threadIdx.x;
  float acc = 0.f;
#pragma unroll
  for (int j = 0; j < KNN; ++j) acc += ew[j] * Y[(size_t)er[j] * F + f];
  Z[(size_t)e * F + f] = acc * (1.0f / 9.0f);
}

// Stage B: out[i,f] = relu(dv2[i] * sum_{e in node i's list} Z[e,f])
template<int F>
__global__ __launch_bounds__(F) void node_gather(const float* __restrict__ Z,
                                                 const int* __restrict__ off,
                                                 const int* __restrict__ elist,
                                                 const float* __restrict__ dv2,
                                                 float* __restrict__ out) {
  int i = blockIdx.x;
  int f = threadIdx.x;
  int s = off[i], epos = off[i + 1];
  float acc = 0.f;
  for (int t = s; t < epos; ++t) acc += Z[(size_t)elist[t] * F + f];
  acc = fmaxf(acc * dv2[i], 0.f);
  out[(size_t)i * F + f] = acc;
}

// Dense P = Y @ W + bias ; 4 rows per block, FO threads (one output col each).
template<int KD, int FO>
__global__ __launch_bounds__(FO) void gemm_bias(const float* __restrict__ Y,
                                                const float* __restrict__ W,
                                                const float* __restrict__ bias,
                                                float* __restrict__ P) {
  __shared__ float ylds[4 * KD];
  int m0 = blockIdx.x * 4;
  int f = threadIdx.x;
  for (int t = threadIdx.x; t < 4 * KD; t += FO)
    ylds[t] = Y[(size_t)m0 * KD + t];
  __syncthreads();
  float a0 = 0.f, a1 = 0.f, a2 = 0.f, a3 = 0.f;
  for (int k = 0; k < KD; k += 4) {
    float w0 = W[(size_t)(k + 0) * FO + f];
    float w1 = W[(size_t)(k + 1) * FO + f];
    float w2 = W[(size_t)(k + 2) * FO + f];
    float w3 = W[(size_t)(k + 3) * FO + f];
    float4 y0 = *reinterpret_cast<const float4*>(&ylds[0 * KD + k]);
    float4 y1 = *reinterpret_cast<const float4*>(&ylds[1 * KD + k]);
    float4 y2 = *reinterpret_cast<const float4*>(&ylds[2 * KD + k]);
    float4 y3 = *reinterpret_cast<const float4*>(&ylds[3 * KD + k]);
    a0 = fmaf(y0.x, w0, fmaf(y0.y, w1, fmaf(y0.z, w2, fmaf(y0.w, w3, a0))));
    a1 = fmaf(y1.x, w0, fmaf(y1.y, w1, fmaf(y1.z, w2, fmaf(y1.w, w3, a1))));
    a2 = fmaf(y2.x, w0, fmaf(y2.y, w1, fmaf(y2.z, w2, fmaf(y2.w, w3, a2))));
    a3 = fmaf(y3.x, w0, fmaf(y3.y, w1, fmaf(y3.z, w2, fmaf(y3.w, w3, a3))));
  }
  float bb = bias[f];
  P[(size_t)(m0 + 0) * FO + f] = a0 + bb;
  P[(size_t)(m0 + 1) * FO + f] = a1 + bb;
  P[(size_t)(m0 + 2) * FO + f] = a2 + bb;
  P[(size_t)(m0 + 3) * FO + f] = a3 + bb;
}

extern "C" void kernel_launch(void* const* d_in, const int* in_sizes, int n_in,
                              void* d_out, int out_size, void* d_ws, size_t ws_size,
                              hipStream_t stream) {
  const float* x   = (const float*)d_in[0];
  const float* adj = (const float*)d_in[1];
  const float* W10 = (const float*)d_in[2];
  const float* b10 = (const float*)d_in[3];
  const float* W11 = (const float*)d_in[4];
  const float* b11 = (const float*)d_in[5];
  const float* W20 = (const float*)d_in[6];
  const float* b20 = (const float*)d_in[7];
  const float* W21 = (const float*)d_in[8];
  const float* b21 = (const float*)d_in[9];
  float* out = (float*)d_out;

  // workspace layout (total ~12.9 MB)
  char* w = (char*)d_ws;
  int*   idx    = (int*)(w + 0);          // 4096*9*4   = 147456
  int*   DV     = (int*)(w + 147456);     // 4096*4     = 16384
  int*   off    = (int*)(w + 163840);     // 4097*4 (padded to 16640)
  int*   cursor = (int*)(w + 180480);     // 16384
  int*   elist  = (int*)(w + 196864);     // 147456
  float* dv2    = (float*)(w + 344320);   // 16384
  float* bufP   = (float*)(w + 360704);               // 4 MB
  float* bufZ   = (float*)(w + 360704 + 4194304);     // 4 MB
  float* bufH   = (float*)(w + 360704 + 2 * 4194304); // 4 MB slot (2 MB used)

  float* x1out = out + (size_t)N_NODES * 256;
  float* x2out = out + (size_t)N_NODES * 256 + (size_t)N_NODES * 128;

  hipMemsetAsync(DV, 0, N_NODES * sizeof(int), stream);
  hipMemsetAsync(cursor, 0, N_NODES * sizeof(int), stream);
  // output 0: x passthrough
  hipMemcpyAsync(out, x, (size_t)N_NODES * 256 * sizeof(float),
                 hipMemcpyDeviceToDevice, stream);

  // hypergraph construction
  topk_kernel<<<1024, 256, 0, stream>>>(adj, idx, DV);
  dv2_kernel<<<16, 256, 0, stream>>>(DV, dv2);
  scan_kernel<<<1, 1024, 0, stream>>>(DV, off);
  fill_csr<<<(N_NODES * KNN + 255) / 256, 256, 0, stream>>>(idx, off, cursor, elist);

  // layer 1: x1 = relu(G @ (relu(G @ (x W10 + b10)) W11 + b11))
  gemm_bias<256, 128><<<N_NODES / 4, 128, 0, stream>>>(x, W10, b10, bufP);
  edge_gather<128><<<N_NODES, 128, 0, stream>>>(bufP, idx, dv2, bufZ);
  node_gather<128><<<N_NODES, 128, 0, stream>>>(bufZ, off, elist, dv2, bufH);
  gemm_bias<128, 128><<<N_NODES / 4, 128, 0, stream>>>(bufH, W11, b11, bufP);
  edge_gather<128><<<N_NODES, 128, 0, stream>>>(bufP, idx, dv2, bufZ);
  node_gather<128><<<N_NODES, 128, 0, stream>>>(bufZ, off, elist, dv2, x1out);

  // layer 2: x2 = relu(G @ (relu(G @ (x1 W20 + b20)) W21 + b21))
  gemm_bias<128, 128><<<N_NODES / 4, 128, 0, stream>>>(x1out, W20, b20, bufP);
  edge_gather<128><<<N_NODES, 128, 0, stream>>>(bufP, idx, dv2, bufZ);
  node_gather<128><<<N_NODES, 128, 0, stream>>>(bufZ, off, elist, dv2, bufH);
  gemm_bias<128, 256><<<N_NODES / 4, 256, 0, stream>>>(bufH, W21, b21, bufP);
  edge_gather<256><<<N_NODES, 256, 0, stream>>>(bufP, idx, dv2, bufZ);
  node_gather<256><<<N_NODES, 256, 0, stream>>>(bufZ, off, elist, dv2, x2out);
}

// Round 2
// 187.049 us; speedup vs baseline: 1.1347x; 1.1347x over previous
//
#include <hip/hip_runtime.h>

#define N_NODES 4096
#define KNN 9
#define CAP 4096

// One block (256 threads) per row. Threshold-collect survivors into LDS,
// then 9 exact argmax rounds (tie-break: value desc, column index asc,
// matching lax.top_k). Fallback collects the entire row if <9 survivors.
__global__ __launch_bounds__(256) void topk_kernel(const float* __restrict__ dis,
                                                   int* __restrict__ idx,
                                                   int* __restrict__ DV) {
  __shared__ float sval[CAP];
  __shared__ int   sidx[CAP];
  __shared__ int   scount;
  __shared__ float wbv[4];
  __shared__ int   wbi[4], wbs[4];
  __shared__ int   outj[KNN];

  const int tid = threadIdx.x;
  const int row = blockIdx.x;
  const float* r = dis + (size_t)row * N_NODES;

  // 16 values per thread, kept in registers (4x float4, coalesced)
  float4 f[4];
#pragma unroll
  for (int i = 0; i < 4; ++i)
    f[i] = *reinterpret_cast<const float4*>(r + i * 1024 + tid * 4);

  float T = 0.99f;
  int n = 0;
  for (int attempt = 0; attempt < 2; ++attempt) {
    if (tid == 0) scount = 0;
    __syncthreads();
#pragma unroll
    for (int i = 0; i < 4; ++i) {
      float vals[4] = {f[i].x, f[i].y, f[i].z, f[i].w};
#pragma unroll
      for (int q = 0; q < 4; ++q) {
        int c = i * 1024 + tid * 4 + q;
        float val = (c == row) ? 0.0f : vals[q];   // ref zeroes the diagonal
        if (val > T) {
          int p = atomicAdd(&scount, 1);
          if (p < CAP) { sval[p] = val; sidx[p] = c; }
        }
      }
    }
    __syncthreads();
    n = scount;
    if (n >= KNN) break;
    T = -3.0e38f;          // exact fallback: collect everything
    __syncthreads();
  }
  if (n > CAP) n = CAP;    // unreachable (CAP == row length), safety

  // 9 rounds of block-wide argmax over survivors
  for (int rnd = 0; rnd < KNN; ++rnd) {
    float bv = -3.1e38f; int bi = 0x7fffffff; int bs = -1;
    for (int s = tid; s < n; s += 256) {
      float v = sval[s]; int c = sidx[s];
      if (v > bv || (v == bv && c < bi)) { bv = v; bi = c; bs = s; }
    }
#pragma unroll
    for (int d = 1; d < 64; d <<= 1) {
      float ov = __shfl_xor(bv, d);
      int   oi = __shfl_xor(bi, d);
      int   os = __shfl_xor(bs, d);
      if (ov > bv || (ov == bv && oi < bi)) { bv = ov; bi = oi; bs = os; }
    }
    int wv = tid >> 6;
    if ((tid & 63) == 0) { wbv[wv] = bv; wbi[wv] = bi; wbs[wv] = bs; }
    __syncthreads();
    if (tid == 0) {
#pragma unroll
      for (int w = 1; w < 4; ++w) {
        if (wbv[w] > bv || (wbv[w] == bv && wbi[w] < bi)) {
          bv = wbv[w]; bi = wbi[w]; bs = wbs[w];
        }
      }
      outj[rnd] = bi;
      if (bs >= 0) sval[bs] = -3.2e38f;   // pop winner
    }
    __syncthreads();
  }

  if (tid == 0) {
    bool has_center = false;
#pragma unroll
    for (int t = 0; t < KNN; ++t) has_center = has_center || (outj[t] == row);
    if (!has_center) outj[KNN - 1] = row;
#pragma unroll
    for (int t = 0; t < KNN; ++t) {
      int j = outj[t];
      idx[row * KNN + t] = j;
      atomicAdd(&DV[j], 1);
    }
  }
}

// Exclusive prefix sum of DV -> off[0..N], plus dv2 = DV^-1/2. Single block.
__global__ __launch_bounds__(1024) void scan_kernel(const int* __restrict__ DV,
                                                    int* __restrict__ off,
                                                    float* __restrict__ dv2) {
  __shared__ int part[1024];
  int tid = threadIdx.x;
  int vals[4]; int s = 0;
#pragma unroll
  for (int q = 0; q < 4; ++q) {
    int d = DV[tid * 4 + q];
    vals[q] = d; s += d;
    dv2[tid * 4 + q] = rsqrtf((float)d);
  }
  part[tid] = s;
  __syncthreads();
  for (int d = 1; d < 1024; d <<= 1) {
    int x = (tid >= d) ? part[tid - d] : 0;
    __syncthreads();
    part[tid] += x;
    __syncthreads();
  }
  int excl = (tid == 0) ? 0 : part[tid - 1];
#pragma unroll
  for (int q = 0; q < 4; ++q) { off[tid * 4 + q] = excl; excl += vals[q]; }
  if (tid == 1023) off[N_NODES] = excl;
}

// Build inverse CSR: for each (hyperedge e, slot j), append e to node idx[e][j]'s list.
__global__ void fill_csr(const int* __restrict__ idx, const int* __restrict__ off,
                         int* __restrict__ cursor, int* __restrict__ elist) {
  int t = blockIdx.x * blockDim.x + threadIdx.x;
  if (t >= N_NODES * KNN) return;
  int e = t / KNN;
  int node = idx[t];
  int p = atomicAdd(&cursor[node], 1);
  elist[off[node] + p] = e;
}

// Stage A: Z[e,f] = (1/9) * sum_{j} dv2[idx[e][j]] * Y[idx[e][j], f]
template<int F>
__global__ __launch_bounds__(F) void edge_gather(const float* __restrict__ Y,
                                                 const int* __restrict__ idx,
                                                 const float* __restrict__ dv2,
                                                 float* __restrict__ Z) {
  __shared__ int er[KNN];
  __shared__ float ew[KNN];
  int e = blockIdx.x;
  if (threadIdx.x < KNN) {
    int r = idx[e * KNN + threadIdx.x];
    er[threadIdx.x] = r;
    ew[threadIdx.x] = dv2[r];
  }
  __syncthreads();
  int f = threadIdx.x;
  float acc = 0.f;
#pragma unroll
  for (int j = 0; j < KNN; ++j) acc += ew[j] * Y[(size_t)er[j] * F + f];
  Z[(size_t)e * F + f] = acc * (1.0f / 9.0f);
}

// Stage B: out[i,f] = relu(dv2[i] * sum_{e in node i's list} Z[e,f])
template<int F>
__global__ __launch_bounds__(F) void node_gather(const float* __restrict__ Z,
                                                 const int* __restrict__ off,
                                                 const int* __restrict__ elist,
                                                 const float* __restrict__ dv2,
                                                 float* __restrict__ out) {
  int i = blockIdx.x;
  int f = threadIdx.x;
  int s = off[i], epos = off[i + 1];
  float acc = 0.f;
  for (int t = s; t < epos; ++t) acc += Z[(size_t)elist[t] * F + f];
  acc = fmaxf(acc * dv2[i], 0.f);
  out[(size_t)i * F + f] = acc;
}

// Dense P = Y @ W + bias ; ROWS rows per block, FO threads (one output col each).
template<int KD, int FO, int ROWS>
__global__ __launch_bounds__(FO) void gemm_bias(const float* __restrict__ Y,
                                                const float* __restrict__ W,
                                                const float* __restrict__ bias,
                                                float* __restrict__ P) {
  __shared__ float ylds[ROWS * KD];
  int m0 = blockIdx.x * ROWS;
  int f = threadIdx.x;
  for (int t = threadIdx.x; t < ROWS * KD; t += FO)
    ylds[t] = Y[(size_t)m0 * KD + t];
  __syncthreads();
  float acc[ROWS];
#pragma unroll
  for (int rr = 0; rr < ROWS; ++rr) acc[rr] = 0.f;
  for (int k = 0; k < KD; k += 4) {
    float w0 = W[(size_t)(k + 0) * FO + f];
    float w1 = W[(size_t)(k + 1) * FO + f];
    float w2 = W[(size_t)(k + 2) * FO + f];
    float w3 = W[(size_t)(k + 3) * FO + f];
#pragma unroll
    for (int rr = 0; rr < ROWS; ++rr) {
      float4 y = *reinterpret_cast<const float4*>(&ylds[rr * KD + k]);
      acc[rr] = fmaf(y.x, w0, fmaf(y.y, w1, fmaf(y.z, w2, fmaf(y.w, w3, acc[rr]))));
    }
  }
  float bb = bias[f];
#pragma unroll
  for (int rr = 0; rr < ROWS; ++rr)
    P[(size_t)(m0 + rr) * FO + f] = acc[rr] + bb;
}

extern "C" void kernel_launch(void* const* d_in, const int* in_sizes, int n_in,
                              void* d_out, int out_size, void* d_ws, size_t ws_size,
                              hipStream_t stream) {
  const float* x   = (const float*)d_in[0];
  const float* adj = (const float*)d_in[1];
  const float* W10 = (const float*)d_in[2];
  const float* b10 = (const float*)d_in[3];
  const float* W11 = (const float*)d_in[4];
  const float* b11 = (const float*)d_in[5];
  const float* W20 = (const float*)d_in[6];
  const float* b20 = (const float*)d_in[7];
  const float* W21 = (const float*)d_in[8];
  const float* b21 = (const float*)d_in[9];
  float* out = (float*)d_out;

  // workspace layout (DV and cursor adjacent -> single memset)
  char* w = (char*)d_ws;
  int*   idx    = (int*)(w + 0);          // 147456
  int*   DV     = (int*)(w + 147456);     // 16384
  int*   cursor = (int*)(w + 163840);     // 16384
  int*   off    = (int*)(w + 180224);     // 16640
  int*   elist  = (int*)(w + 196864);     // 147456
  float* dv2    = (float*)(w + 344320);   // 16384
  float* bufP   = (float*)(w + 360704);               // 4 MB
  float* bufZ   = (float*)(w + 360704 + 4194304);     // 4 MB
  float* bufH   = (float*)(w + 360704 + 2 * 4194304); // 2 MB used

  float* x1out = out + (size_t)N_NODES * 256;
  float* x2out = out + (size_t)N_NODES * 256 + (size_t)N_NODES * 128;

  hipMemsetAsync(DV, 0, 2 * N_NODES * sizeof(int), stream);  // DV + cursor
  // output 0: x passthrough
  hipMemcpyAsync(out, x, (size_t)N_NODES * 256 * sizeof(float),
                 hipMemcpyDeviceToDevice, stream);

  // hypergraph construction
  topk_kernel<<<N_NODES, 256, 0, stream>>>(adj, idx, DV);
  scan_kernel<<<1, 1024, 0, stream>>>(DV, off, dv2);
  fill_csr<<<(N_NODES * KNN + 255) / 256, 256, 0, stream>>>(idx, off, cursor, elist);

  // layer 1: x1 = relu(G @ (relu(G @ (x W10 + b10)) W11 + b11))
  gemm_bias<256, 128, 8><<<N_NODES / 8, 128, 0, stream>>>(x, W10, b10, bufP);
  edge_gather<128><<<N_NODES, 128, 0, stream>>>(bufP, idx, dv2, bufZ);
  node_gather<128><<<N_NODES, 128, 0, stream>>>(bufZ, off, elist, dv2, bufH);
  gemm_bias<128, 128, 8><<<N_NODES / 8, 128, 0, stream>>>(bufH, W11, b11, bufP);
  edge_gather<128><<<N_NODES, 128, 0, stream>>>(bufP, idx, dv2, bufZ);
  node_gather<128><<<N_NODES, 128, 0, stream>>>(bufZ, off, elist, dv2, x1out);

  // layer 2: x2 = relu(G @ (relu(G @ (x1 W20 + b20)) W21 + b21))
  gemm_bias<128, 128, 8><<<N_NODES / 8, 128, 0, stream>>>(x1out, W20, b20, bufP);
  edge_gather<128><<<N_NODES, 128, 0, stream>>>(bufP, idx, dv2, bufZ);
  node_gather<128><<<N_NODES, 128, 0, stream>>>(bufZ, off, elist, dv2, bufH);
  gemm_bias<128, 256, 8><<<N_NODES / 8, 256, 0, stream>>>(bufH, W21, b21, bufP);
  edge_gather<256><<<N_NODES, 256, 0, stream>>>(bufP, idx, dv2, bufZ);
  node_gather<256><<<N_NODES, 256, 0, stream>>>(bufZ, off, elist, dv2, x2out);
}